// Round 8
// baseline (260.343 us; speedup 1.0000x reference)
//
#include <hip/hip_runtime.h>
#include <math.h>

#define N_IMG 128
#define C_DIM 128
#define K_CL  64
#define S_PIX 4096
#define PB    8                 // blocks per image
#define SPB   (S_PIX/PB)        // 512 pixels per block
#define CHK   32                // pixels per chunk
#define NCHK  (SPB/CHK)         // 16
#define NBUF  2                 // X staging buffers (1-deep prefetch)
#define AROW  64                // a' row stride (bf16 elems) = 128B
#define APL   (K_CL*AROW)       // one a' plane (elems)

typedef __attribute__((ext_vector_type(8))) short bf16x8;
typedef __attribute__((ext_vector_type(4))) float f32x4;

__device__ __forceinline__ unsigned short f2bf_rn(float v) {
    unsigned u = __float_as_uint(v);
    unsigned r = u + 0x7fffu + ((u >> 16) & 1u);
    return (unsigned short)(r >> 16);
}
__device__ __forceinline__ float bf2f(unsigned short h) {
    return __uint_as_float(((unsigned)h) << 16);
}

// X-tile slot swizzle: granule sigma of row r lives at slot sigma ^ rho_x(r).
// rho_x(r) = (bitswap2(r&3) << 1) | ((r>>2)&1)  -- injects row bits into both
// high and low slot bits => phase-A scalar reads 2-way, phase-B b128 8/slot.
__device__ __forceinline__ int rho_x(int r) {
    return ((((r & 1) << 1) | ((r >> 1) & 1)) << 1) | ((r >> 2) & 1);
}

// a'-tile: granule G (8 px) of row k at slot ((((k>>2)&3)^(G>>1))<<1)|(G&1)
__device__ __forceinline__ int a_slot(int k, int G) {
    return ((((k >> 2) & 3) ^ (G >> 1)) << 1) | (G & 1);
}

// truncation hi/lo split of 8 floats -> two bf16x8, packed via v_perm
__device__ __forceinline__ void cvt8(const float* v, bf16x8& h, bf16x8& l) {
    union { unsigned w[4]; bf16x8 v8; } H, L;
    #pragma unroll
    for (int p = 0; p < 4; ++p) {
        unsigned u0 = __float_as_uint(v[2*p]);
        unsigned u1 = __float_as_uint(v[2*p+1]);
        float r0 = v[2*p]   - __uint_as_float(u0 & 0xffff0000u);
        float r1 = v[2*p+1] - __uint_as_float(u1 & 0xffff0000u);
        H.w[p] = __builtin_amdgcn_perm(u1, u0, 0x07060302u);
        L.w[p] = __builtin_amdgcn_perm(__float_as_uint(r1), __float_as_uint(r0), 0x07060302u);
    }
    h = H.v8; l = L.v8;
}

// async global->LDS, 16B per lane, lane writes lds + lane*16 (linear)
__device__ __forceinline__ void gll16(const float* g, float* l) {
    __builtin_amdgcn_global_load_lds(
        (const __attribute__((address_space(1))) unsigned int*)(g),
        (__attribute__((address_space(3))) unsigned int*)(l),
        16, 0, 0);
}

// ---- kernel 0: W [K][C] fp32 -> pre-fragmented hi/lo bf16 A-fragments ----
// kdim map: MFMA kdim position p=8g+j (g=lane>>4) <-> channel c = 32t + 4j + g
__global__ void k_prep(const float* __restrict__ w, unsigned short* __restrict__ wf) {
    int i = blockIdx.x * 256 + threadIdx.x;          // 8192
    int j = i & 7, l = (i >> 3) & 63, t = (i >> 9) & 3, m = (i >> 11) & 3;
    int k = 16*m + (l & 15);
    int c = 32*t + 4*j + (l >> 4);
    float v = w[k * C_DIM + c];
    unsigned short h = f2bf_rn(v);
    wf[i]        = h;
    wf[8192 + i] = f2bf_rn(v - bf2f(h));
}

// ---- clear kernel: zero vlad accumulator (4MB) + asum (32KB) ----
__global__ void k_clear(float4* __restrict__ out4, float4* __restrict__ asum4) {
    int i = blockIdx.x * 256 + threadIdx.x;
    f32x4 z = (f32x4)0.f;
    if (i < (N_IMG*K_CL*C_DIM)/4) out4[i] = *(float4*)&z;
    if (i < (N_IMG*K_CL)/4)       asum4[i] = *(float4*)&z;
}

// ---- kernel 1: fused GEMM1(MFMA) -> softmax -> GEMM2(MFMA), 3 blocks/CU ----
__global__ __launch_bounds__(512, 6)
void k_main(const float* __restrict__ x,              // [N][C][S]
            const unsigned short* __restrict__ wf,    // [2][16][64][8] bf16 bits
            const float* __restrict__ bias,           // [K]
            float* __restrict__ vlad,                 // [N][K][C] accumulator (= d_out)
            float* __restrict__ asum)                 // [N][K]
{
    __shared__ float Xs[NBUF][C_DIM*CHK];             // 32KB: x chunk tiles, swizzled
    __shared__ unsigned short aS[2*APL];              // 16KB: a' tile (hi/lo planes)
    __shared__ float redS[2][4][16];                  // 512B: softmax sum exchange

    const int tid  = threadIdx.x;
    const int lane = tid & 63;
    const int wid  = tid >> 6;            // 0..7
    const int lc   = lane & 15;
    const int g    = lane >> 4;

    const int p  = wid & 1;               // phase A: px-tile (16 px)
    const int q  = wid >> 1;              // phase A: k-quarter (1 m-tile)
    const int px = p*16 + lc;
    const int cq = wid * 16;              // phase B: c-slice

    // sp-major grid: all 8 sibling blocks of image n share XCD n%8
    const int n  = blockIdx.x & 127;
    const int sp = blockIdx.x >> 7;
    const float* xn = x + (size_t)n * (C_DIM * S_PIX) + sp * SPB;

    // ---- W fragments for this wave's k-quarter into REGISTERS (anchored) ----
    bf16x8 Wh[4], Wl[4];
    #pragma unroll
    for (int t = 0; t < 4; ++t) {
        Wh[t] = *(const bf16x8*)&wf[((q*4 + t)*64 + lane)*8];
        Wl[t] = *(const bf16x8*)&wf[((16 + q*4 + t)*64 + lane)*8];
    }
    #pragma unroll
    for (int t = 0; t < 4; ++t) {
        asm volatile("" : "+v"(Wh[t]));
        asm volatile("" : "+v"(Wl[t]));
    }
    f32x4 bias_r = *(const f32x4*)&bias[16*q + 4*g];

    f32x4 accV[4];
    #pragma unroll
    for (int m = 0; m < 4; ++m) accV[m] = (f32x4)0.f;
    float asum_acc[4] = {0.f, 0.f, 0.f, 0.f};

    const int r0 = wid * 16;              // this wave's 16 staged rows
    const int Tg = (((g & 1) << 1) | (g >> 1)) << 1;      // phase-A rho high bits
    const int rhoB = rho_x(lc);                            // phase-B rho (c = cq+lc)

    // stage chunk t into Xbuf (2 gll16 per wave; source pre-swizzled)
    auto STAGE = [&](int t, float* Xbuf) {
        #pragma unroll
        for (int h2 = 0; h2 < 2; ++h2) {
            int rowbase = r0 + h2*8;
            int row = rowbase + (lane >> 3);
            int sigma = (lane & 7) ^ rho_x(row);
            const float* gp = xn + (size_t)row * S_PIX + t*CHK + 4*sigma;
            gll16(gp, Xbuf + rowbase * 32);
        }
    };

    // ---- prologue ----
    STAGE(0, &Xs[0][0]);
    asm volatile("s_waitcnt vmcnt(0)" ::: "memory");
    __builtin_amdgcn_s_barrier();
    __builtin_amdgcn_sched_barrier(0);

    #pragma unroll 2
    for (int ch = 0; ch < NCHK; ++ch) {
        const int rb = ch & 1;
        const float* Xb = &Xs[rb][0];

        // ---- fire-and-forget stage of chunk ch+1 ----
        if (ch + 1 < NCHK) STAGE(ch + 1, &Xs[rb ^ 1][0]);

        // ================= Phase A: GEMM1 (1 m-tile) + softmax =================
        float ss = 0.f;
        f32x4 aA = (f32x4)0.f, aB = (f32x4)0.f, aC = (f32x4)0.f;  // 3 indep chains
        #pragma unroll
        for (int t = 0; t < 4; ++t) {
            float xv[8];
            #pragma unroll
            for (int j = 0; j < 8; ++j) {
                int c = 32*t + 4*j + g;                   // kdim remap (matches k_prep)
                int slot = (px >> 2) ^ (Tg | (j & 1));
                xv[j] = Xb[c*32 + slot*4 + (px & 3)];
            }
            #pragma unroll
            for (int j = 0; j < 8; ++j) ss = fmaf(xv[j], xv[j], ss);
            bf16x8 xh, xl;
            cvt8(xv, xh, xl);
            aA = __builtin_amdgcn_mfma_f32_16x16x32_bf16(Wh[t], xh, aA, 0,0,0);
            aB = __builtin_amdgcn_mfma_f32_16x16x32_bf16(Wh[t], xl, aB, 0,0,0);
            aC = __builtin_amdgcn_mfma_f32_16x16x32_bf16(Wl[t], xh, aC, 0,0,0);
        }
        f32x4 accL = aA + aB + aC;
        ss += __shfl_xor(ss, 16); ss += __shfl_xor(ss, 32);
        float rnorm = 1.0f / fmaxf(sqrtf(ss), 1e-12f);

        // no-max softmax: logits bounded (|dot|<=||w_k||~1.15, |b|<=0.5)
        float e[4]; float sm = 0.f;
        #pragma unroll
        for (int jj = 0; jj < 4; ++jj) {
            float t2 = __expf(fmaf(accL[jj], rnorm, bias_r[jj]));
            e[jj] = t2;
            sm += t2;
        }
        sm += __shfl_xor(sm, 16); sm += __shfl_xor(sm, 32);
        if (g == 0) redS[p][q][lc] = sm;

        // ---- B1: red ready (LDS flush only, DMA stays in flight) ----
        asm volatile("s_waitcnt lgkmcnt(0)" ::: "memory");
        __builtin_amdgcn_s_barrier();
        __builtin_amdgcn_sched_barrier(0);

        float S = redS[p][0][lc] + redS[p][1][lc] + redS[p][2][lc] + redS[p][3][lc];
        float coef  = 1.0f / S;
        float coefr = coef * rnorm;

        // write a' hi/lo to aS; accumulate asum (raw a)
        #pragma unroll
        for (int jj = 0; jj < 4; ++jj) {
            float ev = e[jj];
            asum_acc[jj] += ev * coef;
            float ap = ev * coefr;
            unsigned u = __float_as_uint(ap);
            float r = ap - __uint_as_float(u & 0xffff0000u);
            int k = 16*q + 4*g + jj;
            int ix = k*AROW + a_slot(k, px >> 3)*8 + (px & 7);
            aS[ix]       = (unsigned short)(u >> 16);
            aS[APL + ix] = (unsigned short)(__float_as_uint(r) >> 16);
        }

        // ---- B2: aS ready (LDS flush only) ----
        asm volatile("s_waitcnt lgkmcnt(0)" ::: "memory");
        __builtin_amdgcn_s_barrier();
        __builtin_amdgcn_sched_barrier(0);

        // ================= Phase B: GEMM2 (wave's 16-c slice, K=32) ============
        {
            bf16x8 Ah[4], Al[4];
            #pragma unroll
            for (int m = 0; m < 4; ++m) {
                int k = 16*m + lc;
                int off = k*AROW + a_slot(k, g)*8;
                Ah[m] = *(const bf16x8*)&aS[off];
                Al[m] = *(const bf16x8*)&aS[APL + off];
            }
            int c = cq + lc;
            int slot0 = (2*g) ^ rhoB;
            float4 f0 = *(const float4*)&Xb[c*32 + slot0*4];
            float4 f1 = *(const float4*)&Xb[c*32 + (slot0 ^ 1)*4];
            float xv[8] = {f0.x,f0.y,f0.z,f0.w,f1.x,f1.y,f1.z,f1.w};
            bf16x8 xh, xl;
            cvt8(xv, xh, xl);
            #pragma unroll
            for (int m = 0; m < 4; ++m) {
                accV[m] = __builtin_amdgcn_mfma_f32_16x16x32_bf16(Ah[m], xh, accV[m], 0,0,0);
                accV[m] = __builtin_amdgcn_mfma_f32_16x16x32_bf16(Ah[m], xl, accV[m], 0,0,0);
                accV[m] = __builtin_amdgcn_mfma_f32_16x16x32_bf16(Al[m], xh, accV[m], 0,0,0);
            }
        }

        // ---- B3: next chunk's staged data ready; aS + Xs[rb^1] released ----
        if (ch < NCHK - 1) {
            asm volatile("s_waitcnt vmcnt(0)" ::: "memory");
            __builtin_amdgcn_s_barrier();
            __builtin_amdgcn_sched_barrier(0);
        }
    }

    // ---- epilogue: vlad partials -> global atomics ----
    float* vb = vlad + (size_t)n * (K_CL * C_DIM);
    #pragma unroll
    for (int m = 0; m < 4; ++m)
        #pragma unroll
        for (int jj = 0; jj < 4; ++jj)
            atomicAdd(&vb[(16*m + 4*g + jj)*C_DIM + cq + lc], accV[m][jj]);

    // ---- asum: 16-lane butterfly over lc, then atomics ----
    #pragma unroll
    for (int i = 0; i < 4; ++i) {
        float v = asum_acc[i];
        v += __shfl_xor(v, 1); v += __shfl_xor(v, 2);
        v += __shfl_xor(v, 4); v += __shfl_xor(v, 8);
        asum_acc[i] = v;
    }
    if (lc == 0) {
        #pragma unroll
        for (int jj = 0; jj < 4; ++jj)
            atomicAdd(&asum[n*K_CL + 16*q + 4*g + jj], asum_acc[jj]);
    }
}

// ---- kernel 2: subtract a-sum*centroid, intra-norm, global norm ----
__global__ __launch_bounds__(256)
void k_final(float* __restrict__ vlad,          // [N][K*C] in/out (= d_out)
             const float* __restrict__ asum,    // [N][K]
             const float* __restrict__ cent)    // [K][C]
{
    __shared__ float v[K_CL * 132];
    __shared__ float red[K_CL][4];
    __shared__ float rin[K_CL];
    __shared__ float rtot_s;
    const int tid = threadIdx.x;
    const int n   = blockIdx.x;
    float* vb = vlad + (size_t)n * (K_CL * C_DIM);
    const float* as = asum + n * K_CL;

    for (int i = tid; i < K_CL*C_DIM; i += 256) {
        int k = i >> 7, c = i & 127;
        v[k*132 + c] = vb[i] - as[k] * cent[i];
    }
    __syncthreads();
    {
        int k = tid >> 2, p = tid & 3;
        float s2 = 0.f;
        #pragma unroll
        for (int u = 0; u < 32; ++u) { float t = v[k*132 + (u<<2) + p]; s2 = fmaf(t, t, s2); }
        red[k][p] = s2;
    }
    __syncthreads();
    if (tid < K_CL) {
        float s2 = red[tid][0] + red[tid][1] + red[tid][2] + red[tid][3];
        float r  = 1.0f / fmaxf(sqrtf(s2), 1e-12f);
        rin[tid] = r;
        red[tid][0] = s2 * r * r;
    }
    __syncthreads();
    if (tid < 64) {
        float t = red[tid][0];
        t += __shfl_xor(t, 32); t += __shfl_xor(t, 16); t += __shfl_xor(t, 8);
        t += __shfl_xor(t, 4);  t += __shfl_xor(t, 2);  t += __shfl_xor(t, 1);
        if (tid == 0) rtot_s = 1.0f / fmaxf(sqrtf(t), 1e-12f);
    }
    __syncthreads();
    float rt = rtot_s;
    for (int i = tid; i < K_CL*C_DIM; i += 256) {
        vb[i] = v[(i>>7)*132 + (i&127)] * rin[i>>7] * rt;
    }
}

extern "C" void kernel_launch(void* const* d_in, const int* in_sizes, int n_in,
                              void* d_out, int out_size, void* d_ws, size_t ws_size,
                              hipStream_t stream) {
    const float* x    = (const float*)d_in[0];
    const float* w    = (const float*)d_in[1];
    const float* b    = (const float*)d_in[2];
    const float* cent = (const float*)d_in[3];
    float* out = (float*)d_out;
    unsigned short* wf = (unsigned short*)d_ws;           // 32KB
    float* asum = (float*)((char*)d_ws + 32768);          // [N][K]

    k_clear<<<(N_IMG*K_CL*C_DIM/4 + 255)/256, 256, 0, stream>>>(
        (float4*)out, (float4*)asum);
    k_prep<<<32, 256, 0, stream>>>(w, wf);
    k_main<<<N_IMG * PB, 512, 0, stream>>>(x, wf, b, out, asum);
    k_final<<<N_IMG, 256, 0, stream>>>(out, asum, cent);
}

// Round 9
// 139.447 us; speedup vs baseline: 1.8670x; 1.8670x over previous
//
#include <hip/hip_runtime.h>
#include <math.h>

#define N_IMG 128
#define C_DIM 128
#define K_CL  64
#define S_PIX 4096
#define PB    8                 // blocks per image
#define SPB   (S_PIX/PB)        // 512 pixels per block
#define CHK   64                // pixels per chunk
#define NCHK  (SPB/CHK)         // 8
#define NBUF  3                 // X staging buffers
#define AROW  64                // a' row stride (shorts) = 128B
#define APL   (K_CL*AROW)       // one a' plane (4096 shorts = 8KB)

typedef __attribute__((ext_vector_type(8))) short bf16x8;
typedef __attribute__((ext_vector_type(4))) float f32x4;

__device__ __forceinline__ unsigned short f2bf_rn(float v) {
    unsigned u = __float_as_uint(v);
    unsigned r = u + 0x7fffu + ((u >> 16) & 1u);
    return (unsigned short)(r >> 16);
}
__device__ __forceinline__ float bf2f(unsigned short h) {
    return __uint_as_float(((unsigned)h) << 16);
}

// X-tile granule swizzle (16 granules of 16B per 256B row): slot = g16 ^ swzx(c)
__device__ __forceinline__ int swzx(int c) { return ((c & 3) << 1) ^ ((c >> 2) & 7); }
// a'-tile granule swizzle (8 granules of 16B per 128B row): slot = g8 ^ swza(k)
__device__ __forceinline__ int swza(int k) { return ((k >> 2) & 3) ^ (((k >> 1) & 1) << 2); }

// truncation hi/lo split of 8 floats -> two bf16x8, packed via v_perm
__device__ __forceinline__ void cvt8(const float* v, bf16x8& h, bf16x8& l) {
    union { unsigned w[4]; bf16x8 v8; } H, L;
    #pragma unroll
    for (int p = 0; p < 4; ++p) {
        unsigned u0 = __float_as_uint(v[2*p]);
        unsigned u1 = __float_as_uint(v[2*p+1]);
        float r0 = v[2*p]   - __uint_as_float(u0 & 0xffff0000u);
        float r1 = v[2*p+1] - __uint_as_float(u1 & 0xffff0000u);
        H.w[p] = __builtin_amdgcn_perm(u1, u0, 0x07060302u);
        L.w[p] = __builtin_amdgcn_perm(__float_as_uint(r1), __float_as_uint(r0), 0x07060302u);
    }
    h = H.v8; l = L.v8;
}

// async global->LDS, 16B per lane, lane writes lds + lane*16 (linear)
__device__ __forceinline__ void gll16(const float* g, float* l) {
    __builtin_amdgcn_global_load_lds(
        (const __attribute__((address_space(1))) unsigned int*)(g),
        (__attribute__((address_space(3))) unsigned int*)(l),
        16, 0, 0);
}

// ---- kernel 0: W [K][C] fp32 -> pre-fragmented hi/lo bf16 A-fragments ----
// kdim map: MFMA kdim position p=8g+j (g=lane>>4) <-> channel c = 32t + 4j + g
__global__ void k_prep(const float* __restrict__ w, unsigned short* __restrict__ wf) {
    int i = blockIdx.x * 256 + threadIdx.x;          // 8192
    int j = i & 7, l = (i >> 3) & 63, t = (i >> 9) & 3, m = (i >> 11) & 3;
    int k = 16*m + (l & 15);
    int c = 32*t + 4*j + (l >> 4);
    float v = w[k * C_DIM + c];
    unsigned short h = f2bf_rn(v);
    wf[i]        = h;
    wf[8192 + i] = f2bf_rn(v - bf2f(h));
}

// ---- clear kernel: zero vlad accumulator (4MB) + asum (32KB) ----
__global__ void k_clear(float4* __restrict__ out4, float4* __restrict__ asum4) {
    int i = blockIdx.x * 256 + threadIdx.x;
    f32x4 z = (f32x4)0.f;
    if (i < (N_IMG*K_CL*C_DIM)/4) out4[i] = *(float4*)&z;
    if (i < (N_IMG*K_CL)/4)       asum4[i] = *(float4*)&z;
}

// ---- kernel 1: producer/consumer wave-specialized fused kernel ----
// waves 0-3: GEMM1 + softmax on chunk st  -> aS[st&1]
// waves 4-7: GEMM2 on chunk st-1 from aS[(st-1)&1]
__global__ __launch_bounds__(512, 2)
void k_main(const float* __restrict__ x,              // [N][C][S]
            const unsigned short* __restrict__ wf,    // [2][16][64][8] bf16 bits
            const float* __restrict__ bias,           // [K]
            float* __restrict__ vlad,                 // [N][K][C] accumulator (= d_out)
            float* __restrict__ asum)                 // [N][K]
{
    __shared__ float Xs[NBUF][C_DIM*CHK];             // 96KB, swizzled granules
    __shared__ unsigned short aS[2][2*APL];           // 32KB: dbuf x (hi,lo planes)

    const int tid  = threadIdx.x;
    const int lane = tid & 63;
    const int wid  = tid >> 6;            // 0..7
    const int lc   = lane & 15;
    const int g    = lane >> 4;
    const bool isA = wid < 4;
    const int w    = wid & 3;

    // sp-major grid: all 8 sibling blocks of image n share an XCD
    const int n  = blockIdx.x & 127;
    const int sp = blockIdx.x >> 7;
    const float* xn = x + (size_t)n * (C_DIM * S_PIX) + sp * SPB;

    const int r0 = wid * 16;              // this wave's 16 staged rows

    // stage chunk t into Xbuf (4 gll16/wave; global source pre-swizzled)
    auto STAGE = [&](int t, float* Xbuf) {
        #pragma unroll
        for (int i2 = 0; i2 < 4; ++i2) {
            int rowbase = r0 + i2*4;
            int row = rowbase + (lane >> 4);
            const float* gp = xn + (size_t)row * S_PIX + t*CHK
                            + 4*((lane & 15) ^ swzx(row));
            gll16(gp, &Xbuf[rowbase * 64]);
        }
    };

    // ================= role-specific persistent state =================
    // A-state
    bf16x8 Wh[4][4], Wl[4][4];            // A only: W fragments, all 4 m-tiles
    f32x4  bias_r[4];
    float  asum_acc[16];
    const int px  = w*16 + lc;            // A pixel
    const int ab0 = 64*g + (px & 3);      // A-read base (float idx)
    const int sA  = (px >> 2) ^ (g << 1); // A-read slot base (XOR j)
    // B-state
    f32x4 accV[4][2];
    const int swA = ((lc >> 2) & 3) ^ (((lc >> 1) & 1) << 2);  // swza(16m+lc)

    if (isA) {
        #pragma unroll
        for (int m = 0; m < 4; ++m)
            #pragma unroll
            for (int t = 0; t < 4; ++t) {
                Wh[m][t] = *(const bf16x8*)&wf[((m*4 + t)*64 + lane)*8];
                Wl[m][t] = *(const bf16x8*)&wf[((16 + m*4 + t)*64 + lane)*8];
            }
        #pragma unroll
        for (int m = 0; m < 4; ++m)
            #pragma unroll
            for (int t = 0; t < 4; ++t) {
                asm volatile("" : "+v"(Wh[m][t]));
                asm volatile("" : "+v"(Wl[m][t]));
            }
        #pragma unroll
        for (int m = 0; m < 4; ++m) bias_r[m] = *(const f32x4*)&bias[16*m + 4*g];
        #pragma unroll
        for (int i = 0; i < 16; ++i) asum_acc[i] = 0.f;
    } else {
        #pragma unroll
        for (int m = 0; m < 4; ++m) { accV[m][0] = (f32x4)0.f; accV[m][1] = (f32x4)0.f; }
    }

    // ---- prologue: stage chunk 0 ----
    STAGE(0, &Xs[0][0]);
    asm volatile("s_waitcnt vmcnt(0)" ::: "memory");
    __builtin_amdgcn_s_barrier();
    __builtin_amdgcn_sched_barrier(0);

    for (int st = 0; st <= NCHK; ++st) {
        // fire-and-forget stage of chunk st+1
        if (st + 1 < NCHK) STAGE(st + 1, &Xs[(st + 1) % NBUF][0]);

        if (isA) {
            if (st < NCHK) {
                const float* Xb = &Xs[st % NBUF][0];
                unsigned short* aW = &aS[st & 1][0];

                float ss = 0.f;
                f32x4 accL[4];
                #pragma unroll
                for (int m = 0; m < 4; ++m) accL[m] = (f32x4)0.f;

                #pragma unroll
                for (int t = 0; t < 4; ++t) {
                    float xv[8];
                    #pragma unroll
                    for (int j = 0; j < 8; ++j)
                        xv[j] = Xb[2048*t + 256*j + ab0 + ((sA ^ j) << 2)];
                    #pragma unroll
                    for (int j = 0; j < 8; ++j) ss = fmaf(xv[j], xv[j], ss);
                    bf16x8 xh, xl;
                    cvt8(xv, xh, xl);
                    #pragma unroll
                    for (int m = 0; m < 4; ++m) {
                        accL[m] = __builtin_amdgcn_mfma_f32_16x16x32_bf16(Wh[m][t], xh, accL[m], 0,0,0);
                        accL[m] = __builtin_amdgcn_mfma_f32_16x16x32_bf16(Wh[m][t], xl, accL[m], 0,0,0);
                        accL[m] = __builtin_amdgcn_mfma_f32_16x16x32_bf16(Wl[m][t], xh, accL[m], 0,0,0);
                    }
                }
                ss += __shfl_xor(ss, 16); ss += __shfl_xor(ss, 32);
                float rnorm = 1.0f / fmaxf(sqrtf(ss), 1e-12f);

                // no-max softmax over all 64 k (16 in-lane + 4-lane-group butterfly)
                float e[16]; float sm = 0.f;
                #pragma unroll
                for (int m = 0; m < 4; ++m)
                    #pragma unroll
                    for (int jj = 0; jj < 4; ++jj) {
                        float t2 = __expf(fmaf(accL[m][jj], rnorm, bias_r[m][jj]));
                        e[m*4+jj] = t2;
                        sm += t2;
                    }
                sm += __shfl_xor(sm, 16); sm += __shfl_xor(sm, 32);
                float coef  = 1.0f / sm;
                float coefr = coef * rnorm;

                // write a' hi/lo to aS[st&1] (swizzled granules); accumulate asum
                #pragma unroll
                for (int m = 0; m < 4; ++m)
                    #pragma unroll
                    for (int jj = 0; jj < 4; ++jj) {
                        float ev = e[m*4+jj];
                        asum_acc[m*4+jj] += ev * coef;
                        float ap = ev * coefr;
                        unsigned u = __float_as_uint(ap);
                        float r = ap - __uint_as_float(u & 0xffff0000u);
                        int k = 16*m + 4*g + jj;
                        int gA = (px >> 3) ^ g ^ (((jj >> 1) & 1) << 2);
                        int ix = k*AROW + gA*8 + (px & 7);
                        aW[ix]       = (unsigned short)(u >> 16);
                        aW[APL + ix] = (unsigned short)(__float_as_uint(r) >> 16);
                    }
            }
        } else {
            if (st >= 1) {
                const int cb = st - 1;
                const float* Xb = &Xs[cb % NBUF][0];
                const unsigned short* aR = &aS[cb & 1][0];

                #pragma unroll
                for (int ks = 0; ks < 2; ++ks) {
                    bf16x8 Ah[4], Al[4];
                    #pragma unroll
                    for (int m = 0; m < 4; ++m) {
                        int off = (16*m + lc)*AROW + ((4*ks + g) ^ swA)*8;
                        Ah[m] = *(const bf16x8*)&aR[off];
                        Al[m] = *(const bf16x8*)&aR[APL + off];
                    }
                    #pragma unroll
                    for (int nn = 0; nn < 2; ++nn) {
                        int c = w*32 + nn*16 + lc;
                        int slot0 = (8*ks + 2*g) ^ swzx(c);
                        float4 f0 = *(const float4*)&Xb[c*64 + slot0*4];
                        float4 f1 = *(const float4*)&Xb[c*64 + (slot0 ^ 1)*4];
                        float xv[8] = {f0.x,f0.y,f0.z,f0.w,f1.x,f1.y,f1.z,f1.w};
                        bf16x8 xh, xl;
                        cvt8(xv, xh, xl);
                        #pragma unroll
                        for (int m = 0; m < 4; ++m) {
                            accV[m][nn] = __builtin_amdgcn_mfma_f32_16x16x32_bf16(Ah[m], xh, accV[m][nn], 0,0,0);
                            accV[m][nn] = __builtin_amdgcn_mfma_f32_16x16x32_bf16(Ah[m], xl, accV[m][nn], 0,0,0);
                            accV[m][nn] = __builtin_amdgcn_mfma_f32_16x16x32_bf16(Al[m], xh, accV[m][nn], 0,0,0);
                        }
                    }
                }
            }
        }

        // single handoff barrier per step (own stages landed; LDS flushed)
        if (st < NCHK) {
            asm volatile("s_waitcnt vmcnt(0) lgkmcnt(0)" ::: "memory");
            __builtin_amdgcn_s_barrier();
            __builtin_amdgcn_sched_barrier(0);
        }
    }

    // ---- epilogues ----
    if (isA) {
        // asum: butterfly over lc (lanes sharing g), one atomic set per wave
        #pragma unroll
        for (int i = 0; i < 16; ++i) {
            float v = asum_acc[i];
            v += __shfl_xor(v, 1); v += __shfl_xor(v, 2);
            v += __shfl_xor(v, 4); v += __shfl_xor(v, 8);
            asum_acc[i] = v;
        }
        if (lc == 0) {
            #pragma unroll
            for (int m = 0; m < 4; ++m)
                #pragma unroll
                for (int jj = 0; jj < 4; ++jj)
                    atomicAdd(&asum[n*K_CL + 16*m + 4*g + jj], asum_acc[m*4+jj]);
        }
    } else {
        float* vb = vlad + (size_t)n * (K_CL * C_DIM);
        #pragma unroll
        for (int m = 0; m < 4; ++m)
            #pragma unroll
            for (int nn = 0; nn < 2; ++nn)
                #pragma unroll
                for (int jj = 0; jj < 4; ++jj)
                    atomicAdd(&vb[(16*m + 4*g + jj)*C_DIM + w*32 + nn*16 + lc],
                              accV[m][nn][jj]);
    }
}

// ---- kernel 2: subtract a-sum*centroid, intra-norm, global norm ----
__global__ __launch_bounds__(256)
void k_final(float* __restrict__ vlad,          // [N][K*C] in/out (= d_out)
             const float* __restrict__ asum,    // [N][K]
             const float* __restrict__ cent)    // [K][C]
{
    __shared__ float v[K_CL * 132];
    __shared__ float red[K_CL][4];
    __shared__ float rin[K_CL];
    __shared__ float rtot_s;
    const int tid = threadIdx.x;
    const int n   = blockIdx.x;
    float* vb = vlad + (size_t)n * (K_CL * C_DIM);
    const float* as = asum + n * K_CL;

    for (int i = tid; i < K_CL*C_DIM; i += 256) {
        int k = i >> 7, c = i & 127;
        v[k*132 + c] = vb[i] - as[k] * cent[i];
    }
    __syncthreads();
    {
        int k = tid >> 2, p = tid & 3;
        float s2 = 0.f;
        #pragma unroll
        for (int u = 0; u < 32; ++u) { float t = v[k*132 + (u<<2) + p]; s2 = fmaf(t, t, s2); }
        red[k][p] = s2;
    }
    __syncthreads();
    if (tid < K_CL) {
        float s2 = red[tid][0] + red[tid][1] + red[tid][2] + red[tid][3];
        float r  = 1.0f / fmaxf(sqrtf(s2), 1e-12f);
        rin[tid] = r;
        red[tid][0] = s2 * r * r;
    }
    __syncthreads();
    if (tid < 64) {
        float t = red[tid][0];
        t += __shfl_xor(t, 32); t += __shfl_xor(t, 16); t += __shfl_xor(t, 8);
        t += __shfl_xor(t, 4);  t += __shfl_xor(t, 2);  t += __shfl_xor(t, 1);
        if (tid == 0) rtot_s = 1.0f / fmaxf(sqrtf(t), 1e-12f);
    }
    __syncthreads();
    float rt = rtot_s;
    for (int i = tid; i < K_CL*C_DIM; i += 256) {
        vb[i] = v[(i>>7)*132 + (i&127)] * rin[i>>7] * rt;
    }
}

extern "C" void kernel_launch(void* const* d_in, const int* in_sizes, int n_in,
                              void* d_out, int out_size, void* d_ws, size_t ws_size,
                              hipStream_t stream) {
    const float* x    = (const float*)d_in[0];
    const float* w    = (const float*)d_in[1];
    const float* b    = (const float*)d_in[2];
    const float* cent = (const float*)d_in[3];
    float* out = (float*)d_out;
    unsigned short* wf = (unsigned short*)d_ws;           // 32KB
    float* asum = (float*)((char*)d_ws + 32768);          // [N][K]

    k_clear<<<(N_IMG*K_CL*C_DIM/4 + 255)/256, 256, 0, stream>>>(
        (float4*)out, (float4*)asum);
    k_prep<<<32, 256, 0, stream>>>(w, wf);
    k_main<<<N_IMG * PB, 512, 0, stream>>>(x, wf, b, out, asum);
    k_final<<<N_IMG, 256, 0, stream>>>(out, asum, cent);
}